// Round 7
// baseline (312.224 us; speedup 1.0000x reference)
//
#include <hip/hip_runtime.h>

#define D_MODEL 1024
#define TSEQ    4096
#define BATCH   4
#define MROWS   (BATCH * TSEQ)   // 16384
#define KDIM    1024
#define NDIM    1024
#define EPSV    1e-6f

typedef __attribute__((ext_vector_type(8))) short short8;
typedef __attribute__((ext_vector_type(4))) float floatx4;

__device__ inline unsigned short f2bf(float f) {
  unsigned u = __float_as_uint(f);
  unsigned r = (u + 0x7FFFu + ((u >> 16) & 1u)) >> 16;  // RNE
  return (unsigned short)r;
}
__device__ inline float phi_f(float x) { return x > 0.f ? x + 1.f : __expf(x); }

// async global->LDS, 16B per lane (linear dest = wave base + lane*16)
#define GLD16(gp, lp) __builtin_amdgcn_global_load_lds( \
    (const __attribute__((address_space(1))) void*)(gp), \
    (__attribute__((address_space(3))) void*)(lp), 16, 0, 0)

// ---------------- fused prep: fp32->bf16 (x + 4 weights) + zero ksum/kvsum ----
#define NX4 4194304   // x float4 count
#define NW4 262144    // one weight float4 count
#define NZ4 2048      // ksum+kvsum float4 count

__global__ __launch_bounds__(256) void prep_kernel(
    const float* __restrict__ x,  const float* __restrict__ wq,
    const float* __restrict__ wk, const float* __restrict__ wv,
    const float* __restrict__ wg,
    unsigned short* __restrict__ xb,  unsigned short* __restrict__ wqb,
    unsigned short* __restrict__ wkb, unsigned short* __restrict__ wvb,
    unsigned short* __restrict__ wgb, float* __restrict__ zbase)
{
  long i = (long)blockIdx.x * 256 + threadIdx.x;
  const float* src; unsigned short* dst; long j = i;
  if (j < NX4) { src = x; dst = xb; }
  else {
    j -= NX4;
    if (j < NW4) { src = wq; dst = wqb; }
    else { j -= NW4;
      if (j < NW4) { src = wk; dst = wkb; }
      else { j -= NW4;
        if (j < NW4) { src = wv; dst = wvb; }
        else { j -= NW4;
          if (j < NW4) { src = wg; dst = wgb; }
          else { j -= NW4;
            if (j < NZ4) { float4 zz = {0.f,0.f,0.f,0.f}; ((float4*)zbase)[j] = zz; }
            return;
          }
        }
      }
    }
  }
  float4 f = ((const float4*)src)[j];
  ushort4 o;
  o.x = f2bf(f.x); o.y = f2bf(f.y); o.z = f2bf(f.z); o.w = f2bf(f.w);
  ((ushort4*)dst)[j] = o;
}

// ---------------- GEMM geometry --------------------------------------------
// SMALL-BLOCK / MULTI-BLOCK-PER-CU (m97 regime): 256 threads (4 waves),
// tile 128(M) x 64(N per matrix), BK=64, single-buffered LDS (~33 KB),
// __launch_bounds__(256,3) -> ~3 blocks/CU = 3 independent barrier domains.
// Loop is m97-exact: sync -> global_load_lds -> sync(vmcnt drain) -> compute.
// The drain is hidden by the other resident blocks (m114 cross-block overlap)
// instead of by intra-block pipelining (rounds 2-5: all capped at ~25%).
// LDS rows 128 B; XOR swizzle slot^=row&7 on 16B slots (conflicts==0,
// verified r2) via inverse-swizzled GLOBAL source + swizzled ds_read.
#define BM 128
#define BNH 64              // N-cols per matrix per block (= one head for qg)
#define BK 64
#define NSTEP (KDIM / BK)   // 16

// grid: 2048 blocks = 16 bn x 128 bm; bijective XCD swizzle groups same-bn
// blocks on one XCD (B-panels ~1 MB -> L2-resident per XCD).
#define GRID_SWZ(bid, bn, bm) \
  const int sw_ = ((bid) & 7) * 256 + ((bid) >> 3); \
  const int bn = sw_ >> 7; \
  const int bm = sw_ & 127;

// ---------------- phase 1: k/v GEMM with in-register fused reduction --------
// 4 waves: w -> rows [(w>>1)*64, +64), cols [(w&1)*32, +32), dual k+v acc.
__global__ __launch_bounds__(256, 3) void gemm_kv_kernel(
    const unsigned short* __restrict__ A,
    const unsigned short* __restrict__ Wk, const unsigned short* __restrict__ Wv,
    float* __restrict__ ksum, float* __restrict__ kvsum)
{
  __shared__ __align__(16) unsigned short As[BM * BK];    // 16 KB
  __shared__ __align__(16) unsigned short Bk[BNH * BK];   // 8 KB
  __shared__ __align__(16) unsigned short Bv[BNH * BK];   // 8 KB

  GRID_SWZ(blockIdx.x, bn, bm);

  const int tid  = threadIdx.x;
  const int lane = tid & 63;
  const int w    = tid >> 6;           // 0..3
  const int wrow = (w >> 1) * 64;
  const int wc   = (w & 1) * 32;
  const int la   = lane & 15;
  const int l4   = lane >> 4;

  floatx4 ak[4][2], av[4][2];
#pragma unroll
  for (int i = 0; i < 4; i++)
#pragma unroll
    for (int j = 0; j < 2; j++) {
      floatx4 zz = {0.f,0.f,0.f,0.f}; ak[i][j] = zz; av[i][j] = zz;
    }

  const unsigned short* Ablk = A  + (size_t)bm * BM * KDIM;
  const unsigned short* Bkb  = Wk + (size_t)bn * BNH * KDIM;
  const unsigned short* Bvb  = Wv + (size_t)bn * BNH * KDIM;

  // staging offsets (elements), inverse-swizzled global source col
  int aoff[4], aL[4], boff[2], bL[2];
#pragma unroll
  for (int i = 0; i < 4; i++) {
    int s = tid + i * 256; int r = s >> 3;
    aoff[i] = r * KDIM + (((s & 7) ^ (r & 7)) << 3);
    aL[i]   = s * 8;
  }
#pragma unroll
  for (int i = 0; i < 2; i++) {
    int s = tid + i * 256; int r = s >> 3;
    boff[i] = r * KDIM + (((s & 7) ^ (r & 7)) << 3);
    bL[i]   = s * 8;
  }

  // swizzled ds_read slot (row&7 == la&7 for all frag rows)
  const int sl0 = (0 * 4 + l4) ^ (la & 7);
  const int sl1 = (1 * 4 + l4) ^ (la & 7);
  const int aB0 = (wrow + la) * BK + sl0 * 8;
  const int aB1 = (wrow + la) * BK + sl1 * 8;
  const int bB0 = (wc + la) * BK + sl0 * 8;
  const int bB1 = (wc + la) * BK + sl1 * 8;

  for (int kt = 0; kt < KDIM; kt += BK) {
    __syncthreads();                   // readers done with LDS
#pragma unroll
    for (int i = 0; i < 4; ++i) GLD16(Ablk + aoff[i] + kt, As + aL[i]);
#pragma unroll
    for (int i = 0; i < 2; ++i) {
      GLD16(Bkb + boff[i] + kt, Bk + bL[i]);
      GLD16(Bvb + boff[i] + kt, Bv + bL[i]);
    }
    __syncthreads();                   // vmcnt(0) drain (m97 pattern)

    short8 bkf[2][2], bvf[2][2];
#pragma unroll
    for (int j = 0; j < 2; ++j) {
      bkf[j][0] = *(const short8*)(Bk + bB0 + j * (16*BK));
      bkf[j][1] = *(const short8*)(Bk + bB1 + j * (16*BK));
      bvf[j][0] = *(const short8*)(Bv + bB0 + j * (16*BK));
      bvf[j][1] = *(const short8*)(Bv + bB1 + j * (16*BK));
    }
    short8 afA[2][2], afB[2][2];
#pragma unroll
    for (int rp = 0; rp < 2; ++rp) {
      afA[rp][0] = *(const short8*)(As + aB0 + rp * (16*BK));
      afA[rp][1] = *(const short8*)(As + aB1 + rp * (16*BK));
      afB[rp][0] = *(const short8*)(As + aB0 + (2+rp) * (16*BK));
      afB[rp][1] = *(const short8*)(As + aB1 + (2+rp) * (16*BK));
    }
    __builtin_amdgcn_s_setprio(1);
#pragma unroll
    for (int rp = 0; rp < 2; ++rp)
#pragma unroll
      for (int j = 0; j < 2; ++j)
#pragma unroll
        for (int kk = 0; kk < 2; ++kk) {
          ak[rp][j] = __builtin_amdgcn_mfma_f32_16x16x32_bf16(
              afA[rp][kk], bkf[j][kk], ak[rp][j], 0, 0, 0);
          av[rp][j] = __builtin_amdgcn_mfma_f32_16x16x32_bf16(
              afA[rp][kk], bvf[j][kk], av[rp][j], 0, 0, 0);
        }
#pragma unroll
    for (int rp = 0; rp < 2; ++rp)
#pragma unroll
      for (int j = 0; j < 2; ++j)
#pragma unroll
        for (int kk = 0; kk < 2; ++kk) {
          ak[2+rp][j] = __builtin_amdgcn_mfma_f32_16x16x32_bf16(
              afB[rp][kk], bkf[j][kk], ak[2+rp][j], 0, 0, 0);
          av[2+rp][j] = __builtin_amdgcn_mfma_f32_16x16x32_bf16(
              afB[rp][kk], bvf[j][kk], av[2+rp][j], 0, 0, 0);
        }
    __builtin_amdgcn_s_setprio(0);
  }

  // ---- fused column reduction ----
  const int b = bm >> 5;               // 32 bm-blocks (128 rows) per batch
  float kp[2] = {0.f, 0.f};
  float vp[2] = {0.f, 0.f};
#pragma unroll
  for (int j = 0; j < 2; j++)
#pragma unroll
    for (int i = 0; i < 4; i++)
#pragma unroll
      for (int r = 0; r < 4; r++) {
        float kk = phi_f(ak[i][j][r]);
        kp[j] += kk;
        vp[j] += kk * av[i][j][r];
      }
#pragma unroll
  for (int j = 0; j < 2; j++) {
    kp[j] += __shfl_xor(kp[j], 16, 64); kp[j] += __shfl_xor(kp[j], 32, 64);
    vp[j] += __shfl_xor(vp[j], 16, 64); vp[j] += __shfl_xor(vp[j], 32, 64);
  }
  if (lane < 16) {
#pragma unroll
    for (int j = 0; j < 2; j++) {
      int col = bn * BNH + wc + j * 16 + lane;
      atomicAdd(ksum  + (size_t)b * D_MODEL + col, kp[j]);
      atomicAdd(kvsum + (size_t)b * D_MODEL + col, vp[j]);
    }
  }
}

// ---------------- phase 2: q/g GEMM with fused finalize ---------------------
// 4 waves: w=0,1 -> q rows [0,64)/[64,128); w=2,3 -> g same rows. Block's 64
// cols = exactly one head -> s,z reduce fully in-wave.
__global__ __launch_bounds__(256, 3) void gemm_qg_kernel(
    const unsigned short* __restrict__ A,
    const unsigned short* __restrict__ Wq, const unsigned short* __restrict__ Wg,
    const float* __restrict__ x, const float* __restrict__ bg,
    const float* __restrict__ ksum, const float* __restrict__ kvsum,
    float* __restrict__ out)
{
  __shared__ __align__(16) unsigned short As[BM * BK];    // 16 KB
  __shared__ __align__(16) unsigned short Bq[BNH * BK];   // 8 KB
  __shared__ __align__(16) unsigned short Bg[BNH * BK];   // 8 KB
  __shared__ float o_lds[BM];          // one head per block

  GRID_SWZ(blockIdx.x, bn, bm);

  const int tid  = threadIdx.x;
  const int lane = tid & 63;
  const int w    = tid >> 6;           // 0..3
  const int is_g = w >> 1;
  const int wr   = (w & 1) * 64;
  const int la   = lane & 15;
  const int l4   = lane >> 4;

  floatx4 acc[4][4];
#pragma unroll
  for (int i = 0; i < 4; i++)
#pragma unroll
    for (int j = 0; j < 4; j++) { floatx4 zz = {0.f,0.f,0.f,0.f}; acc[i][j] = zz; }

  const unsigned short* Ablk = A  + (size_t)bm * BM * KDIM;
  const unsigned short* Bqb  = Wq + (size_t)bn * BNH * KDIM;
  const unsigned short* Bgb  = Wg + (size_t)bn * BNH * KDIM;

  int aoff[4], aL[4], boff[2], bL[2];
#pragma unroll
  for (int i = 0; i < 4; i++) {
    int s = tid + i * 256; int r = s >> 3;
    aoff[i] = r * KDIM + (((s & 7) ^ (r & 7)) << 3);
    aL[i]   = s * 8;
  }
#pragma unroll
  for (int i = 0; i < 2; i++) {
    int s = tid + i * 256; int r = s >> 3;
    boff[i] = r * KDIM + (((s & 7) ^ (r & 7)) << 3);
    bL[i]   = s * 8;
  }

  const int sl0 = (0 * 4 + l4) ^ (la & 7);
  const int sl1 = (1 * 4 + l4) ^ (la & 7);
  const int aB0 = (wr + la) * BK + sl0 * 8;
  const int aB1 = (wr + la) * BK + sl1 * 8;
  const int bB0 = la * BK + sl0 * 8;
  const int bB1 = la * BK + sl1 * 8;

  const unsigned short* Bsm = is_g ? Bg : Bq;

  for (int kt = 0; kt < KDIM; kt += BK) {
    __syncthreads();
#pragma unroll
    for (int i = 0; i < 4; ++i) GLD16(Ablk + aoff[i] + kt, As + aL[i]);
#pragma unroll
    for (int i = 0; i < 2; ++i) {
      GLD16(Bqb + boff[i] + kt, Bq + bL[i]);
      GLD16(Bgb + boff[i] + kt, Bg + bL[i]);
    }
    __syncthreads();                   // vmcnt(0) drain (m97 pattern)

    short8 bf[4][2];
#pragma unroll
    for (int j = 0; j < 4; ++j) {
      bf[j][0] = *(const short8*)(Bsm + bB0 + j * (16*BK));
      bf[j][1] = *(const short8*)(Bsm + bB1 + j * (16*BK));
    }
    short8 afA[2][2], afB[2][2];
#pragma unroll
    for (int rp = 0; rp < 2; ++rp) {
      afA[rp][0] = *(const short8*)(As + aB0 + rp * (16*BK));
      afA[rp][1] = *(const short8*)(As + aB1 + rp * (16*BK));
      afB[rp][0] = *(const short8*)(As + aB0 + (2+rp) * (16*BK));
      afB[rp][1] = *(const short8*)(As + aB1 + (2+rp) * (16*BK));
    }
    __builtin_amdgcn_s_setprio(1);
#pragma unroll
    for (int rp = 0; rp < 2; ++rp)
#pragma unroll
      for (int j = 0; j < 4; ++j)
#pragma unroll
        for (int kk = 0; kk < 2; ++kk)
          acc[rp][j] = __builtin_amdgcn_mfma_f32_16x16x32_bf16(
              afA[rp][kk], bf[j][kk], acc[rp][j], 0, 0, 0);
#pragma unroll
    for (int rp = 0; rp < 2; ++rp)
#pragma unroll
      for (int j = 0; j < 4; ++j)
#pragma unroll
        for (int kk = 0; kk < 2; ++kk)
          acc[2+rp][j] = __builtin_amdgcn_mfma_f32_16x16x32_bf16(
              afB[rp][kk], bf[j][kk], acc[2+rp][j], 0, 0, 0);
    __builtin_amdgcn_s_setprio(0);
  }

  // ---- fused finalize ----
  const int b  = bm >> 5;
  const int ro = l4 * 4;
  const int co = la;

  if (!is_g) {
    float kvv[4], ksv[4];
#pragma unroll
    for (int j = 0; j < 4; j++) {
      int col = bn * BNH + j * 16 + co;
      kvv[j] = kvsum[(size_t)b * D_MODEL + col];
      ksv[j] = ksum [(size_t)b * D_MODEL + col];
    }
#pragma unroll
    for (int i = 0; i < 4; i++)
#pragma unroll
      for (int r = 0; r < 4; r++) {
        float s = 0.f, z = 0.f;
#pragma unroll
        for (int j = 0; j < 4; j++) {
          float qq = phi_f(acc[i][j][r]);
          s += qq * kvv[j]; z += qq * ksv[j];
        }
#pragma unroll
        for (int m = 1; m < 16; m <<= 1) {
          s += __shfl_xor(s, m, 64);
          z += __shfl_xor(z, m, 64);
        }
        if (co == 0) o_lds[wr + i * 16 + ro + r] = s / (z + EPSV);
      }
  }
  __syncthreads();
  if (is_g) {
    float bgv[4];
#pragma unroll
    for (int j = 0; j < 4; j++) bgv[j] = bg[bn * BNH + j * 16 + co];
#pragma unroll
    for (int i = 0; i < 4; i++)
#pragma unroll
      for (int r = 0; r < 4; r++) {
        int rowl = wr + i * 16 + ro + r;
        int grow = bm * BM + rowl;
        float ov = o_lds[rowl];
#pragma unroll
        for (int j = 0; j < 4; j++) {
          int gcol = bn * BNH + j * 16 + co;
          float gt = 1.f / (1.f + __expf(-(acc[i][j][r] + bgv[j])));
          float xv = x[(size_t)grow * D_MODEL + gcol];
          out[(size_t)grow * D_MODEL + gcol] = gt * ov + (1.f - gt) * xv;
        }
      }
  }
}

extern "C" void kernel_launch(void* const* d_in, const int* in_sizes, int n_in,
                              void* d_out, int out_size, void* d_ws, size_t ws_size,
                              hipStream_t stream) {
  (void)in_sizes; (void)n_in; (void)out_size; (void)ws_size;
  const float* x  = (const float*)d_in[0];
  const float* Wq = (const float*)d_in[1];
  const float* Wk = (const float*)d_in[2];
  const float* Wv = (const float*)d_in[3];
  /* d_in[4] = Wo — unused by the reference */
  const float* Wg = (const float*)d_in[5];
  const float* bg = (const float*)d_in[6];
  float* out = (float*)d_out;

  char* ws = (char*)d_ws;
  const size_t xel = (size_t)MROWS * D_MODEL;
  const size_t wel = (size_t)NDIM * KDIM;
  unsigned short* xbf = (unsigned short*)ws; ws += xel * 2;
  unsigned short* wqb = (unsigned short*)ws; ws += wel * 2;
  unsigned short* wkb = (unsigned short*)ws; ws += wel * 2;
  unsigned short* wvb = (unsigned short*)ws; ws += wel * 2;
  unsigned short* wgb = (unsigned short*)ws; ws += wel * 2;
  float* ksum  = (float*)ws; ws += (size_t)BATCH * D_MODEL * 4;  // contiguous
  float* kvsum = (float*)ws; ws += (size_t)BATCH * D_MODEL * 4;

  // 1) fused converts + zero
  const long total4 = (long)NX4 + 4L * NW4 + NZ4;
  prep_kernel<<<(int)((total4 + 255) / 256), 256, 0, stream>>>(
      x, Wq, Wk, Wv, Wg, xbf, wqb, wkb, wvb, wgb, ksum);

  // 2) phase 1: k/v with fused reduction (2048 blocks = 16 bn x 128 bm)
  gemm_kv_kernel<<<2048, 256, 0, stream>>>(xbf, wkb, wvb, ksum, kvsum);

  // 3) phase 2: q/g with fused finalize
  gemm_qg_kernel<<<2048, 256, 0, stream>>>(xbf, wqb, wgb, x, bg, ksum, kvsum, out);
}